// Round 2
// baseline (532.895 us; speedup 1.0000x reference)
//
#include <hip/hip_runtime.h>
#include <cstdint>

// Problem constants
#define D_DIM  2048
#define T_DIM  4096
#define B_DIM  2
#define M_DIM  8192   // B*T
#define DG_DIM 2048
#define N2_DIM 8192   // D*W (W=4)
#define K_DIM  2048
#define NT_TILES (K_DIM / 64)   // 32 K-tiles of 64

typedef __bf16 bf16x8 __attribute__((ext_vector_type(8)));
typedef __bf16 bf16x4 __attribute__((ext_vector_type(4)));
typedef float  f32x4  __attribute__((ext_vector_type(4)));

__device__ __forceinline__ void gload_lds16(const void* g, void* l) {
  __builtin_amdgcn_global_load_lds(
      (__attribute__((address_space(1))) void*)g,
      (__attribute__((address_space(3))) void*)l, 16, 0, 0);
}

__device__ __forceinline__ float silu_f(float a) {
  return a / (1.f + __expf(-a));
}

// ---------------------------------------------------------------------------
// Casts
// ---------------------------------------------------------------------------
__global__ void cast_f32_bf16(const float* __restrict__ src,
                              __bf16* __restrict__ dst, int n4) {
  int i = blockIdx.x * blockDim.x + threadIdx.x;
  if (i >= n4) return;
  float4 v = ((const float4*)src)[i];
  bf16x4 o;
  o[0] = (__bf16)v.x; o[1] = (__bf16)v.y; o[2] = (__bf16)v.z; o[3] = (__bf16)v.w;
  ((bf16x4*)dst)[i] = o;
}

// w2 row-permutation for the 256-wide tile / interleaved wave layout.
// GEMM column c = n0 + wn*16 + j*64 + ln; column c holds original row
// k = 4*d + j with d = 64*(c>>8) + 16*wn + ln, so each lane's 4 j-fragments
// are the 4 taps of one d.
__global__ void cast_permute_w2(const float* __restrict__ src,
                                __bf16* __restrict__ dst, int n4) {
  int i = blockIdx.x * blockDim.x + threadIdx.x;
  if (i >= n4) return;
  const int row = i >> 9;            // dest row c (512 float4 per row of 2048)
  const int pos = i & 511;
  const int blk = row >> 8;          // 256-col tile
  const int cw  = row & 255;
  const int j   = cw >> 6;           // tap
  const int wn  = (cw >> 4) & 3;
  const int ln  = cw & 15;
  const int d   = blk * 64 + wn * 16 + ln;
  const int k   = 4 * d + j;         // original w2 row
  float4 v = ((const float4*)src)[(size_t)k * 512 + pos];
  bf16x4 o;
  o[0] = (__bf16)v.x; o[1] = (__bf16)v.y; o[2] = (__bf16)v.z; o[3] = (__bf16)v.w;
  ((bf16x4*)dst)[i] = o;
}

// ---------------------------------------------------------------------------
// 256x256 tile, BK=64, 8 waves (2M x 4N interleaved), 4 phases per K-tile,
// counted vmcnt (T3+T4) + setprio (T5) + CROSS-PHASE PRE-READS: each phase's
// ds_reads are issued one phase early, inside the previous phase's MFMA
// region, so LDS latency hides under MFMA instead of sitting between
// barriers.  Read schedule:  P4(t-1): aL(t)+b0(t) [after vmcnt(6) -> tile t
// landed];  P1(t): aH(t);  P2(t): b1(t);  P3(t): none.
// Staging per phase (one half-unit = 2 global_load_lds):
//   P1 -> (t+1, B1), P2 -> (t+2, A0), P3 -> (t+2, B0), P4 -> (t+2, A1),
//   then vmcnt(6) at P4 retires exactly tile t+1's 4 units.
// Region-lifetime check (incl. clamped tail): every staged region's last
// reader completes at the lgkmcnt(0) >=1 barrier before the overwriting
// stage is issued.
// ---------------------------------------------------------------------------

__device__ __forceinline__ void stage_unit(const __bf16* src0, const __bf16* src1,
                                           __bf16* sX, int s, int hf,
                                           int lq0, int lq1) {
  const int k0 = (s < NT_TILES) ? (s * 64) : 0;       // clamp keeps vmcnt exact
  __bf16* dst = sX + ((s & 1) * 2 + hf) * 8192;
  const size_t goff = (size_t)hf * 128 * K_DIM + k0;
  gload_lds16(src0 + goff, dst + lq0);
  gload_lds16(src1 + goff, dst + lq1);
}

__device__ __forceinline__ void read4(bf16x8 dst[4][2], const __bf16* base,
                                      const int off[4][2]) {
#pragma unroll
  for (int i = 0; i < 4; i++) {
    dst[i][0] = *(const bf16x8*)(base + off[i][0]);
    dst[i][1] = *(const bf16x8*)(base + off[i][1]);
  }
}

__device__ __forceinline__ void read2(bf16x8 dst[2][2], const __bf16* base,
                                      const int off[2][2]) {
#pragma unroll
  for (int j = 0; j < 2; j++) {
    dst[j][0] = *(const bf16x8*)(base + off[j][0]);
    dst[j][1] = *(const bf16x8*)(base + off[j][1]);
  }
}

__device__ __forceinline__ void mmaq(f32x4 acc[8][4], int ib, int jb,
                                     const bf16x8 a[4][2], const bf16x8 b[2][2]) {
#pragma unroll
  for (int kk = 0; kk < 2; kk++)
#pragma unroll
    for (int i = 0; i < 4; i++)
#pragma unroll
      for (int j = 0; j < 2; j++)
        acc[ib + i][jb + j] = __builtin_amdgcn_mfma_f32_16x16x32_bf16(
            a[i][kk], b[j][kk], acc[ib + i][jb + j], 0, 0, 0);
}

__device__ __forceinline__ void phase_mid() {
  __builtin_amdgcn_s_barrier();
  asm volatile("s_waitcnt lgkmcnt(0)" ::: "memory");
  __builtin_amdgcn_sched_barrier(0);
  __builtin_amdgcn_s_setprio(1);
}

__device__ __forceinline__ void phase_end() {
  __builtin_amdgcn_s_setprio(0);
  __builtin_amdgcn_s_barrier();
}

__device__ __forceinline__ void gemm_core(const __bf16* __restrict__ A,
                                          const __bf16* __restrict__ B,
                                          int m0, int n0,
                                          __bf16* sA, __bf16* sB,
                                          f32x4 acc[8][4]) {
  constexpr int K = K_DIM;
  const int t    = threadIdx.x;       // 0..511
  const int lane = t & 63;
  const int wv   = t >> 6;
  const int wm   = wv >> 2;           // 0..1
  const int wn   = wv & 3;            // 0..3
  const int ln   = lane & 15, qd = lane >> 4;

  // Staging source addresses: linear LDS dest chunk q = inst*512 + t;
  // row = q>>3, slot = q&7, global chunk = slot ^ (row&7) (pre-swizzle).
  const __bf16 *a_src0, *a_src1, *b_src0, *b_src1;
  int lq0, lq1;
  {
    int q = t, row = q >> 3, cg = (q & 7) ^ (row & 7);
    a_src0 = A + (size_t)(m0 + row) * K + cg * 8;
    b_src0 = B + (size_t)(n0 + row) * K + cg * 8;
    lq0 = q * 8;
    q = 512 + t; row = q >> 3; cg = (q & 7) ^ (row & 7);
    a_src1 = A + (size_t)(m0 + row) * K + cg * 8;
    b_src1 = B + (size_t)(n0 + row) * K + cg * 8;
    lq1 = q * 8;
  }

  // Fragment LDS offsets within a half-region (same for both halves).
  int aoff[4][2], boff[2][2];
#pragma unroll
  for (int i = 0; i < 4; i++)
#pragma unroll
    for (int kk = 0; kk < 2; kk++) {
      const int row = wm * 16 + i * 32 + ln;
      aoff[i][kk] = row * 64 + (((kk * 4 + qd) ^ (row & 7)) << 3);
    }
#pragma unroll
  for (int j = 0; j < 2; j++)
#pragma unroll
    for (int kk = 0; kk < 2; kk++) {
      const int row = j * 64 + wn * 16 + ln;
      boff[j][kk] = row * 64 + (((kk * 4 + qd) ^ (row & 7)) << 3);
    }

  bf16x8 aL[4][2], aH[4][2], b0[2][2], b1[2][2];

  // Prologue: tile0 {A0,B0,A1,B1} + tile1 {A0,B0,A1}  (14 loads)
  stage_unit(a_src0, a_src1, sA, 0, 0, lq0, lq1);
  stage_unit(b_src0, b_src1, sB, 0, 0, lq0, lq1);
  stage_unit(a_src0, a_src1, sA, 0, 1, lq0, lq1);
  stage_unit(b_src0, b_src1, sB, 0, 1, lq0, lq1);
  stage_unit(a_src0, a_src1, sA, 1, 0, lq0, lq1);
  stage_unit(b_src0, b_src1, sB, 1, 0, lq0, lq1);
  stage_unit(a_src0, a_src1, sA, 1, 1, lq0, lq1);
  asm volatile("s_waitcnt vmcnt(6)" ::: "memory");   // tile0 fully landed
  __builtin_amdgcn_s_barrier();
  // Pre-read tile0's P1 fragments (aL, b0) — "P4(-1)".
  read4(aL, sA, aoff);
  read2(b0, sB, boff);

  for (int t0 = 0; t0 < NT_TILES; ++t0) {
    const int p = t0 & 1;
    const __bf16* curA = sA + p * 16384;
    const __bf16* curB = sB + p * 16384;
    const __bf16* nxtA = sA + (p ^ 1) * 16384;
    const __bf16* nxtB = sB + (p ^ 1) * 16384;

    // ---- P1: MFMA (iL,jL); pre-read aH(t); stage (t+1, B1)
    stage_unit(b_src0, b_src1, sB, t0 + 1, 1, lq0, lq1);
    phase_mid();
    read4(aH, curA + 8192, aoff);
    mmaq(acc, 0, 0, aL, b0);
    phase_end();

    // ---- P2: MFMA (iH,jL); pre-read b1(t); stage (t+2, A0)
    stage_unit(a_src0, a_src1, sA, t0 + 2, 0, lq0, lq1);
    phase_mid();
    read2(b1, curB + 8192, boff);
    mmaq(acc, 4, 0, aH, b0);
    phase_end();

    // ---- P3: MFMA (iL,jH); stage (t+2, B0)
    stage_unit(b_src0, b_src1, sB, t0 + 2, 0, lq0, lq1);
    phase_mid();
    mmaq(acc, 0, 2, aL, b1);
    phase_end();

    // ---- P4: stage (t+2, A1); counted vmcnt -> tile t+1 complete;
    //          MFMA (iH,jH); pre-read aL(t+1), b0(t+1) under the MFMA.
    stage_unit(a_src0, a_src1, sA, t0 + 2, 1, lq0, lq1);
    asm volatile("s_waitcnt vmcnt(6)" ::: "memory");
    __builtin_amdgcn_s_barrier();
    __builtin_amdgcn_sched_barrier(0);
    __builtin_amdgcn_s_setprio(1);
    read4(aL, nxtA, aoff);
    read2(b0, nxtB, boff);
    mmaq(acc, 4, 2, aH, b1);
    __builtin_amdgcn_s_setprio(0);
    __builtin_amdgcn_s_barrier();
  }
  // Drain clamped tail staging before LDS is reused/deallocated.
  asm volatile("s_waitcnt vmcnt(0)" ::: "memory");
}

// ---------------------------------------------------------------------------
// GEMM1: H = silu(x_bf16 @ w1_bf16^T).  Grid 8x32: natural dispatch already
// gives column-per-XCD (all 32 co-resident blocks share one B-panel) — no
// swizzle needed.
// ---------------------------------------------------------------------------
__global__ __launch_bounds__(512) void gemm1_silu(
    const __bf16* __restrict__ A, const __bf16* __restrict__ B,
    __bf16* __restrict__ H) {
  __shared__ __bf16 sA[4 * 8192];
  __shared__ __bf16 sB[4 * 8192];
  const int m0 = blockIdx.y * 256, n0 = blockIdx.x * 256;
  f32x4 acc[8][4] = {};
  gemm_core(A, B, m0, n0, sA, sB, acc);

  const int lane = threadIdx.x & 63;
  const int wv   = threadIdx.x >> 6;
  const int wm   = wv >> 2, wn = wv & 3;
  const int ln   = lane & 15, qd = lane >> 4;
#pragma unroll
  for (int i = 0; i < 8; i++) {
    const int row0 = m0 + wm * 16 + i * 32 + qd * 4;
#pragma unroll
    for (int j = 0; j < 4; j++) {
      const int col = n0 + wn * 16 + j * 64 + ln;
#pragma unroll
      for (int r = 0; r < 4; r++)
        H[(size_t)(row0 + r) * DG_DIM + col] = (__bf16)silu_f(acc[i][j][r]);
    }
  }
}

// ---------------------------------------------------------------------------
// GEMM2 + fused causal depthwise conv + silu.  B = permuted w2; lane owns
// d = (n0>>2) + wn*16 + ln; its 4 j-fragments are taps w=0..3 of that d.
// XCD-chunked bijective swizzle (nwg=1024 = 8*128): XCD k's co-resident
// blocks share one A-panel; B streams row-synchronized from L3.
// ---------------------------------------------------------------------------
__global__ __launch_bounds__(512) void gemm2_conv_silu(
    const __bf16* __restrict__ A, const __bf16* __restrict__ B,
    const float* __restrict__ b2, const float* __restrict__ x,
    float* __restrict__ out) {
  __shared__ __bf16 sA[4 * 8192];
  __shared__ __bf16 sB[4 * 8192];
  const int bid  = blockIdx.y * 32 + blockIdx.x;       // dispatch order
  const int tile = (bid & 7) * 128 + (bid >> 3);       // bijective: 1024 = 8*128
  const int m0 = (tile >> 5) * 256;
  const int n0 = (tile & 31) * 256;
  f32x4 acc[8][4] = {};
  gemm_core(A, B, m0, n0, sA, sB, acc);

  const int lane = threadIdx.x & 63;
  const int wv   = threadIdx.x >> 6;
  const int wm   = wv >> 2, wn = wv & 3;
  const int ln   = lane & 15, qd = lane >> 4;

  const int d = (n0 >> 2) + wn * 16 + ln;
  const float4 bias = *(const float4*)(b2 + 4 * d);

#pragma unroll
  for (int i = 0; i < 8; i++) {
    const int m_base = m0 + wm * 16 + i * 32 + qd * 4;   // + r
    const int b  = m_base >> 12;                          // T=4096
    const int tb = m_base & 4095;
    // taps: x[b, tb + s - 3, d] for s = r + j in [0,6]
    float xv[7];
#pragma unroll
    for (int s = 0; s < 7; s++) {
      const int tp = tb + s - 3;
      xv[s] = (tp >= 0) ? x[((size_t)((b << 12) + tp)) * D_DIM + d] : 0.f;
    }
#pragma unroll
    for (int r = 0; r < 4; r++) {
      float y = (acc[i][0][r] + bias.x) * xv[r + 0]
              + (acc[i][1][r] + bias.y) * xv[r + 1]
              + (acc[i][2][r] + bias.z) * xv[r + 2]
              + (acc[i][3][r] + bias.w) * xv[r + 3];
      out[(size_t)(m_base + r) * D_DIM + d] = silu_f(y);
    }
  }
}

extern "C" void kernel_launch(void* const* d_in, const int* in_sizes, int n_in,
                              void* d_out, int out_size, void* d_ws, size_t ws_size,
                              hipStream_t stream) {
  (void)in_sizes; (void)n_in; (void)out_size; (void)ws_size;
  const float* x  = (const float*)d_in[0];
  const float* w1 = (const float*)d_in[1];
  const float* w2 = (const float*)d_in[2];
  const float* b2 = (const float*)d_in[3];
  float* out = (float*)d_out;

  __bf16* xb  = (__bf16*)d_ws;                        // 8192*2048
  __bf16* w1b = xb  + (size_t)M_DIM * D_DIM;          // 2048*2048
  __bf16* w2b = w1b + (size_t)DG_DIM * D_DIM;         // 8192*2048 (permuted)
  __bf16* hb  = w2b + (size_t)N2_DIM * DG_DIM;        // 8192*2048

  {
    int n4 = M_DIM * D_DIM / 4;
    cast_f32_bf16<<<(n4 + 255) / 256, 256, 0, stream>>>(x, xb, n4);
  }
  {
    int n4 = DG_DIM * D_DIM / 4;
    cast_f32_bf16<<<(n4 + 255) / 256, 256, 0, stream>>>(w1, w1b, n4);
  }
  {
    int n4 = N2_DIM * DG_DIM / 4;
    cast_permute_w2<<<(n4 + 255) / 256, 256, 0, stream>>>(w2, w2b, n4);
  }

  gemm1_silu<<<dim3(DG_DIM / 256, M_DIM / 256), 512, 0, stream>>>(xb, w1b, hb);
  gemm2_conv_silu<<<dim3(N2_DIM / 256, M_DIM / 256), 512, 0, stream>>>(
      hb, w2b, b2, x, out);
}

// Round 3
// 511.043 us; speedup vs baseline: 1.0428x; 1.0428x over previous
//
#include <hip/hip_runtime.h>
#include <cstdint>

// Problem constants
#define D_DIM  2048
#define T_DIM  4096
#define B_DIM  2
#define M_DIM  8192   // B*T
#define DG_DIM 2048
#define N2_DIM 8192   // D*W (W=4)
#define K_DIM  2048
#define NT_TILES (K_DIM / 64)   // 32 K-tiles of 64

typedef __bf16 bf16x8 __attribute__((ext_vector_type(8)));
typedef __bf16 bf16x4 __attribute__((ext_vector_type(4)));
typedef float  f32x4  __attribute__((ext_vector_type(4)));

__device__ __forceinline__ void gload_lds16(const void* g, void* l) {
  __builtin_amdgcn_global_load_lds(
      (__attribute__((address_space(1))) void*)g,
      (__attribute__((address_space(3))) void*)l, 16, 0, 0);
}

__device__ __forceinline__ float silu_f(float a) {
  return a / (1.f + __expf(-a));
}

// ---------------------------------------------------------------------------
// Casts
// ---------------------------------------------------------------------------
__global__ void cast_f32_bf16(const float* __restrict__ src,
                              __bf16* __restrict__ dst, int n4) {
  int i = blockIdx.x * blockDim.x + threadIdx.x;
  if (i >= n4) return;
  float4 v = ((const float4*)src)[i];
  bf16x4 o;
  o[0] = (__bf16)v.x; o[1] = (__bf16)v.y; o[2] = (__bf16)v.z; o[3] = (__bf16)v.w;
  ((bf16x4*)dst)[i] = o;
}

// w2 row-permutation for the 256-wide tile / interleaved wave layout.
// GEMM column c = n0 + wn*16 + j*64 + ln; column c holds original row
// k = 4*d + j with d = 64*(c>>8) + 16*wn + ln, so each lane's 4 j-fragments
// are the 4 taps of one d.
__global__ void cast_permute_w2(const float* __restrict__ src,
                                __bf16* __restrict__ dst, int n4) {
  int i = blockIdx.x * blockDim.x + threadIdx.x;
  if (i >= n4) return;
  const int row = i >> 9;            // dest row c (512 float4 per row of 2048)
  const int pos = i & 511;
  const int blk = row >> 8;          // 256-col tile
  const int cw  = row & 255;
  const int j   = cw >> 6;           // tap
  const int wn  = (cw >> 4) & 3;
  const int ln  = cw & 15;
  const int d   = blk * 64 + wn * 16 + ln;
  const int k   = 4 * d + j;         // original w2 row
  float4 v = ((const float4*)src)[(size_t)k * 512 + pos];
  bf16x4 o;
  o[0] = (__bf16)v.x; o[1] = (__bf16)v.y; o[2] = (__bf16)v.z; o[3] = (__bf16)v.w;
  ((bf16x4*)dst)[i] = o;
}

// ---------------------------------------------------------------------------
// 256x256 tile, BK=64, 8 waves (2M x 4N interleaved), 4 phases per K-tile,
// counted vmcnt (T3+T4) + setprio (T5) + CROSS-PHASE PRE-READS: each phase's
// ds_reads are issued one phase early, inside the previous phase's MFMA
// region, so LDS latency hides under MFMA instead of sitting between
// barriers.  Read schedule:  P4(t-1): aL(t)+b0(t) [after vmcnt(6) -> tile t
// landed];  P1(t): aH(t);  P2(t): b1(t);  P3(t): none.
// Staging per phase (one half-unit = 2 global_load_lds):
//   P1 -> (t+1, B1), P2 -> (t+2, A0), P3 -> (t+2, B0), P4 -> (t+2, A1),
//   then vmcnt(6) at P4 retires exactly tile t+1's 4 units.
// NOTE (R2 lesson): NO XCD swizzle on either GEMM — natural dispatch keeps
// 4 B-panels (4 MB) resident per XCD-L2; the chunked swizzle doubled
// FETCH_SIZE (252->600 MB) and cost 25 us.
// ---------------------------------------------------------------------------

__device__ __forceinline__ void stage_unit(const __bf16* src0, const __bf16* src1,
                                           __bf16* sX, int s, int hf,
                                           int lq0, int lq1) {
  const int k0 = (s < NT_TILES) ? (s * 64) : 0;       // clamp keeps vmcnt exact
  __bf16* dst = sX + ((s & 1) * 2 + hf) * 8192;
  const size_t goff = (size_t)hf * 128 * K_DIM + k0;
  gload_lds16(src0 + goff, dst + lq0);
  gload_lds16(src1 + goff, dst + lq1);
}

__device__ __forceinline__ void read4(bf16x8 dst[4][2], const __bf16* base,
                                      const int off[4][2]) {
#pragma unroll
  for (int i = 0; i < 4; i++) {
    dst[i][0] = *(const bf16x8*)(base + off[i][0]);
    dst[i][1] = *(const bf16x8*)(base + off[i][1]);
  }
}

__device__ __forceinline__ void read2(bf16x8 dst[2][2], const __bf16* base,
                                      const int off[2][2]) {
#pragma unroll
  for (int j = 0; j < 2; j++) {
    dst[j][0] = *(const bf16x8*)(base + off[j][0]);
    dst[j][1] = *(const bf16x8*)(base + off[j][1]);
  }
}

__device__ __forceinline__ void mmaq(f32x4 acc[8][4], int ib, int jb,
                                     const bf16x8 a[4][2], const bf16x8 b[2][2]) {
#pragma unroll
  for (int kk = 0; kk < 2; kk++)
#pragma unroll
    for (int i = 0; i < 4; i++)
#pragma unroll
      for (int j = 0; j < 2; j++)
        acc[ib + i][jb + j] = __builtin_amdgcn_mfma_f32_16x16x32_bf16(
            a[i][kk], b[j][kk], acc[ib + i][jb + j], 0, 0, 0);
}

__device__ __forceinline__ void phase_mid() {
  __builtin_amdgcn_s_barrier();
  asm volatile("s_waitcnt lgkmcnt(0)" ::: "memory");
  __builtin_amdgcn_sched_barrier(0);
  __builtin_amdgcn_s_setprio(1);
}

__device__ __forceinline__ void phase_end() {
  __builtin_amdgcn_s_setprio(0);
  __builtin_amdgcn_s_barrier();
}

__device__ __forceinline__ void gemm_core(const __bf16* __restrict__ A,
                                          const __bf16* __restrict__ B,
                                          int m0, int n0,
                                          __bf16* sA, __bf16* sB,
                                          f32x4 acc[8][4]) {
  constexpr int K = K_DIM;
  const int t    = threadIdx.x;       // 0..511
  const int lane = t & 63;
  const int wv   = t >> 6;
  const int wm   = wv >> 2;           // 0..1
  const int wn   = wv & 3;            // 0..3
  const int ln   = lane & 15, qd = lane >> 4;

  // Staging source addresses: linear LDS dest chunk q = inst*512 + t;
  // row = q>>3, slot = q&7, global chunk = slot ^ (row&7) (pre-swizzle).
  const __bf16 *a_src0, *a_src1, *b_src0, *b_src1;
  int lq0, lq1;
  {
    int q = t, row = q >> 3, cg = (q & 7) ^ (row & 7);
    a_src0 = A + (size_t)(m0 + row) * K + cg * 8;
    b_src0 = B + (size_t)(n0 + row) * K + cg * 8;
    lq0 = q * 8;
    q = 512 + t; row = q >> 3; cg = (q & 7) ^ (row & 7);
    a_src1 = A + (size_t)(m0 + row) * K + cg * 8;
    b_src1 = B + (size_t)(n0 + row) * K + cg * 8;
    lq1 = q * 8;
  }

  // Fragment LDS offsets within a half-region (same for both halves).
  int aoff[4][2], boff[2][2];
#pragma unroll
  for (int i = 0; i < 4; i++)
#pragma unroll
    for (int kk = 0; kk < 2; kk++) {
      const int row = wm * 16 + i * 32 + ln;
      aoff[i][kk] = row * 64 + (((kk * 4 + qd) ^ (row & 7)) << 3);
    }
#pragma unroll
  for (int j = 0; j < 2; j++)
#pragma unroll
    for (int kk = 0; kk < 2; kk++) {
      const int row = j * 64 + wn * 16 + ln;
      boff[j][kk] = row * 64 + (((kk * 4 + qd) ^ (row & 7)) << 3);
    }

  bf16x8 aL[4][2], aH[4][2], b0[2][2], b1[2][2];

  // Prologue: tile0 {A0,B0,A1,B1} + tile1 {A0,B0,A1}  (14 loads)
  stage_unit(a_src0, a_src1, sA, 0, 0, lq0, lq1);
  stage_unit(b_src0, b_src1, sB, 0, 0, lq0, lq1);
  stage_unit(a_src0, a_src1, sA, 0, 1, lq0, lq1);
  stage_unit(b_src0, b_src1, sB, 0, 1, lq0, lq1);
  stage_unit(a_src0, a_src1, sA, 1, 0, lq0, lq1);
  stage_unit(b_src0, b_src1, sB, 1, 0, lq0, lq1);
  stage_unit(a_src0, a_src1, sA, 1, 1, lq0, lq1);
  asm volatile("s_waitcnt vmcnt(6)" ::: "memory");   // tile0 fully landed
  __builtin_amdgcn_s_barrier();
  // Pre-read tile0's P1 fragments (aL, b0) — "P4(-1)".
  read4(aL, sA, aoff);
  read2(b0, sB, boff);

  for (int t0 = 0; t0 < NT_TILES; ++t0) {
    const int p = t0 & 1;
    const __bf16* curA = sA + p * 16384;
    const __bf16* curB = sB + p * 16384;
    const __bf16* nxtA = sA + (p ^ 1) * 16384;
    const __bf16* nxtB = sB + (p ^ 1) * 16384;

    // ---- P1: MFMA (iL,jL); pre-read aH(t); stage (t+1, B1)
    stage_unit(b_src0, b_src1, sB, t0 + 1, 1, lq0, lq1);
    phase_mid();
    read4(aH, curA + 8192, aoff);
    mmaq(acc, 0, 0, aL, b0);
    phase_end();

    // ---- P2: MFMA (iH,jL); pre-read b1(t); stage (t+2, A0)
    stage_unit(a_src0, a_src1, sA, t0 + 2, 0, lq0, lq1);
    phase_mid();
    read2(b1, curB + 8192, boff);
    mmaq(acc, 4, 0, aH, b0);
    phase_end();

    // ---- P3: MFMA (iL,jH); stage (t+2, B0)
    stage_unit(b_src0, b_src1, sB, t0 + 2, 0, lq0, lq1);
    phase_mid();
    mmaq(acc, 0, 2, aL, b1);
    phase_end();

    // ---- P4: stage (t+2, A1); counted vmcnt -> tile t+1 complete;
    //          MFMA (iH,jH); pre-read aL(t+1), b0(t+1) under the MFMA.
    stage_unit(a_src0, a_src1, sA, t0 + 2, 1, lq0, lq1);
    asm volatile("s_waitcnt vmcnt(6)" ::: "memory");
    __builtin_amdgcn_s_barrier();
    __builtin_amdgcn_sched_barrier(0);
    __builtin_amdgcn_s_setprio(1);
    read4(aL, nxtA, aoff);
    read2(b0, nxtB, boff);
    mmaq(acc, 4, 2, aH, b1);
    __builtin_amdgcn_s_setprio(0);
    __builtin_amdgcn_s_barrier();
  }
  // Drain clamped tail staging before LDS is reused/deallocated.
  asm volatile("s_waitcnt vmcnt(0)" ::: "memory");
}

// ---------------------------------------------------------------------------
// GEMM1: H = silu(x_bf16 @ w1_bf16^T).  Natural dispatch: column-per-XCD,
// B-panel resident in each XCD L2.
// ---------------------------------------------------------------------------
__global__ __launch_bounds__(512) void gemm1_silu(
    const __bf16* __restrict__ A, const __bf16* __restrict__ B,
    __bf16* __restrict__ H) {
  __shared__ __bf16 sA[4 * 8192];
  __shared__ __bf16 sB[4 * 8192];
  const int m0 = blockIdx.y * 256, n0 = blockIdx.x * 256;
  f32x4 acc[8][4] = {};
  gemm_core(A, B, m0, n0, sA, sB, acc);

  const int lane = threadIdx.x & 63;
  const int wv   = threadIdx.x >> 6;
  const int wm   = wv >> 2, wn = wv & 3;
  const int ln   = lane & 15, qd = lane >> 4;
#pragma unroll
  for (int i = 0; i < 8; i++) {
    const int row0 = m0 + wm * 16 + i * 32 + qd * 4;
#pragma unroll
    for (int j = 0; j < 4; j++) {
      const int col = n0 + wn * 16 + j * 64 + ln;
#pragma unroll
      for (int r = 0; r < 4; r++)
        H[(size_t)(row0 + r) * DG_DIM + col] = (__bf16)silu_f(acc[i][j][r]);
    }
  }
}

// ---------------------------------------------------------------------------
// GEMM2 + fused causal depthwise conv + silu.  B = permuted w2; lane owns
// d = (n0>>2) + wn*16 + ln; its 4 j-fragments are taps w=0..3 of that d.
// Natural dispatch (R2 lesson: swizzle doubled FETCH, reverted).
// ---------------------------------------------------------------------------
__global__ __launch_bounds__(512) void gemm2_conv_silu(
    const __bf16* __restrict__ A, const __bf16* __restrict__ B,
    const float* __restrict__ b2, const float* __restrict__ x,
    float* __restrict__ out) {
  __shared__ __bf16 sA[4 * 8192];
  __shared__ __bf16 sB[4 * 8192];
  const int m0 = blockIdx.y * 256, n0 = blockIdx.x * 256;
  f32x4 acc[8][4] = {};
  gemm_core(A, B, m0, n0, sA, sB, acc);

  const int lane = threadIdx.x & 63;
  const int wv   = threadIdx.x >> 6;
  const int wm   = wv >> 2, wn = wv & 3;
  const int ln   = lane & 15, qd = lane >> 4;

  const int d = (n0 >> 2) + wn * 16 + ln;
  const float4 bias = *(const float4*)(b2 + 4 * d);

#pragma unroll
  for (int i = 0; i < 8; i++) {
    const int m_base = m0 + wm * 16 + i * 32 + qd * 4;   // + r
    const int b  = m_base >> 12;                          // T=4096
    const int tb = m_base & 4095;
    // taps: x[b, tb + s - 3, d] for s = r + j in [0,6]
    float xv[7];
#pragma unroll
    for (int s = 0; s < 7; s++) {
      const int tp = tb + s - 3;
      xv[s] = (tp >= 0) ? x[((size_t)((b << 12) + tp)) * D_DIM + d] : 0.f;
    }
#pragma unroll
    for (int r = 0; r < 4; r++) {
      float y = (acc[i][0][r] + bias.x) * xv[r + 0]
              + (acc[i][1][r] + bias.y) * xv[r + 1]
              + (acc[i][2][r] + bias.z) * xv[r + 2]
              + (acc[i][3][r] + bias.w) * xv[r + 3];
      out[(size_t)(m_base + r) * D_DIM + d] = silu_f(y);
    }
  }
}

extern "C" void kernel_launch(void* const* d_in, const int* in_sizes, int n_in,
                              void* d_out, int out_size, void* d_ws, size_t ws_size,
                              hipStream_t stream) {
  (void)in_sizes; (void)n_in; (void)out_size; (void)ws_size;
  const float* x  = (const float*)d_in[0];
  const float* w1 = (const float*)d_in[1];
  const float* w2 = (const float*)d_in[2];
  const float* b2 = (const float*)d_in[3];
  float* out = (float*)d_out;

  __bf16* xb  = (__bf16*)d_ws;                        // 8192*2048
  __bf16* w1b = xb  + (size_t)M_DIM * D_DIM;          // 2048*2048
  __bf16* w2b = w1b + (size_t)DG_DIM * D_DIM;         // 8192*2048 (permuted)
  __bf16* hb  = w2b + (size_t)N2_DIM * DG_DIM;        // 8192*2048

  {
    int n4 = M_DIM * D_DIM / 4;
    cast_f32_bf16<<<(n4 + 255) / 256, 256, 0, stream>>>(x, xb, n4);
  }
  {
    int n4 = DG_DIM * D_DIM / 4;
    cast_f32_bf16<<<(n4 + 255) / 256, 256, 0, stream>>>(w1, w1b, n4);
  }
  {
    int n4 = N2_DIM * DG_DIM / 4;
    cast_permute_w2<<<(n4 + 255) / 256, 256, 0, stream>>>(w2, w2b, n4);
  }

  gemm1_silu<<<dim3(DG_DIM / 256, M_DIM / 256), 512, 0, stream>>>(xb, w1b, hb);
  gemm2_conv_silu<<<dim3(N2_DIM / 256, M_DIM / 256), 512, 0, stream>>>(
      hb, w2b, b2, x, out);
}

// Round 4
// 476.445 us; speedup vs baseline: 1.1185x; 1.0726x over previous
//
#include <hip/hip_runtime.h>
#include <cstdint>

// Problem constants
#define D_DIM  2048
#define T_DIM  4096
#define B_DIM  2
#define M_DIM  8192   // B*T
#define DG_DIM 2048
#define N2_DIM 8192   // D*W (W=4)
#define K_DIM  2048
#define NT_TILES (K_DIM / 64)   // 32 K-tiles of 64

typedef __bf16 bf16x8 __attribute__((ext_vector_type(8)));
typedef __bf16 bf16x4 __attribute__((ext_vector_type(4)));
typedef float  f32x4  __attribute__((ext_vector_type(4)));

__device__ __forceinline__ void gload_lds16(const void* g, void* l) {
  __builtin_amdgcn_global_load_lds(
      (__attribute__((address_space(1))) void*)g,
      (__attribute__((address_space(3))) void*)l, 16, 0, 0);
}

__device__ __forceinline__ float silu_f(float a) {
  return a / (1.f + __expf(-a));
}

// ---------------------------------------------------------------------------
// Casts
// ---------------------------------------------------------------------------
__global__ void cast_f32_bf16(const float* __restrict__ src,
                              __bf16* __restrict__ dst, int n4) {
  int i = blockIdx.x * blockDim.x + threadIdx.x;
  if (i >= n4) return;
  float4 v = ((const float4*)src)[i];
  bf16x4 o;
  o[0] = (__bf16)v.x; o[1] = (__bf16)v.y; o[2] = (__bf16)v.z; o[3] = (__bf16)v.w;
  ((bf16x4*)dst)[i] = o;
}

// w2 row-permutation: GEMM column c = n0 + wn*16 + j*64 + ln holds original
// row k = 4*d + j with d = 64*(c>>8) + 16*wn + ln, so each lane's 4
// j-fragments are the 4 taps of one d.
__global__ void cast_permute_w2(const float* __restrict__ src,
                                __bf16* __restrict__ dst, int n4) {
  int i = blockIdx.x * blockDim.x + threadIdx.x;
  if (i >= n4) return;
  const int row = i >> 9;            // dest row c (512 float4 per row of 2048)
  const int pos = i & 511;
  const int blk = row >> 8;          // 256-col tile
  const int cw  = row & 255;
  const int j   = cw >> 6;           // tap
  const int wn  = (cw >> 4) & 3;
  const int ln  = cw & 15;
  const int d   = blk * 64 + wn * 16 + ln;
  const int k   = 4 * d + j;         // original w2 row
  float4 v = ((const float4*)src)[(size_t)k * 512 + pos];
  bf16x4 o;
  o[0] = (__bf16)v.x; o[1] = (__bf16)v.y; o[2] = (__bf16)v.z; o[3] = (__bf16)v.w;
  ((bf16x4*)dst)[i] = o;
}

// ---------------------------------------------------------------------------
// 256x256 tile, BK=64, 8 waves (2M x 4N interleaved).  R4 structure:
// TWO barriers per K-tile (was 8), whole-tile fragment prefetch in registers.
//
// Per tile t (parity p = t&1):
//   [ stage B1(t+1); 16 MFMA; stage A0(t+2); 16 MFMA; stage B0(t+2);
//     16 MFMA; stage A1(t+2); 16 MFMA ]      // MFMA region: zero LDS deps
//   vmcnt(6)                                  // retires ALL of tile t+1
//   barrier                                   // publish tile t+1 to all waves
//   24 x ds_read_b128: full fragment set of tile t+1 (parity p^1)
//   lgkmcnt(0); sched_barrier                 // reads complete (WAR publish)
//   barrier                                   // next body's stages may begin
//
// Hazard audit: (RAW) reads after vmcnt(6)+barrier see all waves' loads for
// t+1. (WAR) stages in body t overwrite only parity-p regions, whose reads
// completed before the last barrier (they were the tail reads of body t-1).
// Clamped tail stages (s>=32) also only overwrite post-read regions.
// vmcnt accounting: per body 8 loads [B1(t+1), A0/B0/A1(t+2)]; at vmcnt(6)
// newest-6 = A0/B0/A1(t+2) remain, everything through B1(t+1) retired.
// NOTE (R2): natural dispatch only — XCD swizzle doubled FETCH (252->600MB).
// ---------------------------------------------------------------------------

__device__ __forceinline__ void stage_unit(const __bf16* src, __bf16* sX,
                                           int s, int hf, int lq0) {
  const int k0 = (s < NT_TILES) ? (s * 64) : 0;       // clamp keeps vmcnt exact
  __bf16* dst = sX + ((s & 1) * 2 + hf) * 8192;
  const size_t goff = (size_t)hf * 128 * K_DIM + k0;
  gload_lds16(src + goff, dst + lq0);
  gload_lds16(src + goff + (size_t)64 * K_DIM, dst + lq0 + 4096);
}

__device__ __forceinline__ void read4(bf16x8 dst[4][2], const __bf16* base,
                                      const int off[4][2]) {
#pragma unroll
  for (int i = 0; i < 4; i++) {
    dst[i][0] = *(const bf16x8*)(base + off[i][0]);
    dst[i][1] = *(const bf16x8*)(base + off[i][1]);
  }
}

__device__ __forceinline__ void read2(bf16x8 dst[2][2], const __bf16* base,
                                      const int off[2][2]) {
#pragma unroll
  for (int j = 0; j < 2; j++) {
    dst[j][0] = *(const bf16x8*)(base + off[j][0]);
    dst[j][1] = *(const bf16x8*)(base + off[j][1]);
  }
}

__device__ __forceinline__ void mmaq(f32x4 acc[8][4], int ib, int jb,
                                     const bf16x8 a[4][2], const bf16x8 b[2][2]) {
  __builtin_amdgcn_s_setprio(1);
#pragma unroll
  for (int kk = 0; kk < 2; kk++)
#pragma unroll
    for (int i = 0; i < 4; i++)
#pragma unroll
      for (int j = 0; j < 2; j++)
        acc[ib + i][jb + j] = __builtin_amdgcn_mfma_f32_16x16x32_bf16(
            a[i][kk], b[j][kk], acc[ib + i][jb + j], 0, 0, 0);
  __builtin_amdgcn_s_setprio(0);
}

__device__ __forceinline__ void gemm_core(const __bf16* __restrict__ A,
                                          const __bf16* __restrict__ B,
                                          int m0, int n0,
                                          __bf16* sA, __bf16* sB,
                                          f32x4 acc[8][4]) {
  constexpr int K = K_DIM;
  const int t    = threadIdx.x;       // 0..511
  const int lane = t & 63;
  const int wv   = t >> 6;
  const int wm   = wv >> 2;           // 0..1
  const int wn   = wv & 3;            // 0..3
  const int ln   = lane & 15, qd = lane >> 4;

  // Staging source: linear LDS dest chunk q = t (first 64 rows) and
  // q = 512 + t (folded into stage_unit's +64*K / +4096).  Pre-swizzled
  // global chunk = (q&7) ^ (row&7).
  const __bf16 *a_src, *b_src;
  int lq0;
  {
    int q = t, row = q >> 3, cg = (q & 7) ^ (row & 7);
    a_src = A + (size_t)(m0 + row) * K + cg * 8;
    b_src = B + (size_t)(n0 + row) * K + cg * 8;
    lq0 = q * 8;
  }

  // Fragment LDS offsets within a half-region (same for both halves).
  int aoff[4][2], boff[2][2];
#pragma unroll
  for (int i = 0; i < 4; i++)
#pragma unroll
    for (int kk = 0; kk < 2; kk++) {
      const int row = wm * 16 + i * 32 + ln;
      aoff[i][kk] = row * 64 + (((kk * 4 + qd) ^ (row & 7)) << 3);
    }
#pragma unroll
  for (int j = 0; j < 2; j++)
#pragma unroll
    for (int kk = 0; kk < 2; kk++) {
      const int row = j * 64 + wn * 16 + ln;
      boff[j][kk] = row * 64 + (((kk * 4 + qd) ^ (row & 7)) << 3);
    }

  const __bf16* A_p0 = sA;           const __bf16* A_p1 = sA + 16384;
  const __bf16* B_p0 = sB;           const __bf16* B_p1 = sB + 16384;

  bf16x8 aL[4][2], aH[4][2], b0[2][2], b1[2][2];

  // Prologue: stage tile0 {A0,B0,A1,B1} + tile1 {A0,B0,A1}  (14 loads)
  stage_unit(a_src, sA, 0, 0, lq0);
  stage_unit(b_src, sB, 0, 0, lq0);
  stage_unit(a_src, sA, 0, 1, lq0);
  stage_unit(b_src, sB, 0, 1, lq0);
  stage_unit(a_src, sA, 1, 0, lq0);
  stage_unit(b_src, sB, 1, 0, lq0);
  stage_unit(a_src, sA, 1, 1, lq0);
  asm volatile("s_waitcnt vmcnt(6)" ::: "memory");   // tile0 fully landed
  __builtin_amdgcn_s_barrier();
  __builtin_amdgcn_sched_barrier(0);
  // Prefetch full fragment set of tile0 (parity 0).
  read4(aL, A_p0, aoff);
  read4(aH, A_p0 + 8192, aoff);
  read2(b0, B_p0, boff);
  read2(b1, B_p0 + 8192, boff);
  asm volatile("s_waitcnt lgkmcnt(0)" ::: "memory");
  __builtin_amdgcn_sched_barrier(0);
  __builtin_amdgcn_s_barrier();
  __builtin_amdgcn_sched_barrier(0);

  for (int it = 0; it < NT_TILES / 2; ++it) {
    // ================= tile t0 = 2*it (parity 0), tail-reads parity 1 ======
    {
      const int s1 = 2 * it + 1, s2 = 2 * it + 2;
      stage_unit(b_src, sB, s1, 1, lq0);
      mmaq(acc, 0, 0, aL, b0);
      stage_unit(a_src, sA, s2, 0, lq0);
      mmaq(acc, 4, 0, aH, b0);
      stage_unit(b_src, sB, s2, 0, lq0);
      mmaq(acc, 0, 2, aL, b1);
      stage_unit(a_src, sA, s2, 1, lq0);
      mmaq(acc, 4, 2, aH, b1);
      asm volatile("s_waitcnt vmcnt(6)" ::: "memory");
      __builtin_amdgcn_s_barrier();
      __builtin_amdgcn_sched_barrier(0);
      read4(aL, A_p1, aoff);
      read4(aH, A_p1 + 8192, aoff);
      read2(b0, B_p1, boff);
      read2(b1, B_p1 + 8192, boff);
      asm volatile("s_waitcnt lgkmcnt(0)" ::: "memory");
      __builtin_amdgcn_sched_barrier(0);
      __builtin_amdgcn_s_barrier();
      __builtin_amdgcn_sched_barrier(0);
    }
    // ================= tile t1 = 2*it+1 (parity 1), tail-reads parity 0 ====
    {
      const int s1 = 2 * it + 2, s2 = 2 * it + 3;
      stage_unit(b_src, sB, s1, 1, lq0);
      mmaq(acc, 0, 0, aL, b0);
      stage_unit(a_src, sA, s2, 0, lq0);
      mmaq(acc, 4, 0, aH, b0);
      stage_unit(b_src, sB, s2, 0, lq0);
      mmaq(acc, 0, 2, aL, b1);
      stage_unit(a_src, sA, s2, 1, lq0);
      mmaq(acc, 4, 2, aH, b1);
      asm volatile("s_waitcnt vmcnt(6)" ::: "memory");
      __builtin_amdgcn_s_barrier();
      __builtin_amdgcn_sched_barrier(0);
      read4(aL, A_p0, aoff);
      read4(aH, A_p0 + 8192, aoff);
      read2(b0, B_p0, boff);
      read2(b1, B_p0 + 8192, boff);
      asm volatile("s_waitcnt lgkmcnt(0)" ::: "memory");
      __builtin_amdgcn_sched_barrier(0);
      __builtin_amdgcn_s_barrier();
      __builtin_amdgcn_sched_barrier(0);
    }
  }
  // Drain clamped tail staging before LDS is reused/deallocated.
  asm volatile("s_waitcnt vmcnt(0)" ::: "memory");
}

// ---------------------------------------------------------------------------
// GEMM1: H = silu(x_bf16 @ w1_bf16^T).  Natural dispatch (column-per-XCD).
// ---------------------------------------------------------------------------
__global__ __launch_bounds__(512) void gemm1_silu(
    const __bf16* __restrict__ A, const __bf16* __restrict__ B,
    __bf16* __restrict__ H) {
  __shared__ __bf16 sA[4 * 8192];
  __shared__ __bf16 sB[4 * 8192];
  const int m0 = blockIdx.y * 256, n0 = blockIdx.x * 256;
  f32x4 acc[8][4] = {};
  gemm_core(A, B, m0, n0, sA, sB, acc);

  const int lane = threadIdx.x & 63;
  const int wv   = threadIdx.x >> 6;
  const int wm   = wv >> 2, wn = wv & 3;
  const int ln   = lane & 15, qd = lane >> 4;
#pragma unroll
  for (int i = 0; i < 8; i++) {
    const int row0 = m0 + wm * 16 + i * 32 + qd * 4;
#pragma unroll
    for (int j = 0; j < 4; j++) {
      const int col = n0 + wn * 16 + j * 64 + ln;
#pragma unroll
      for (int r = 0; r < 4; r++)
        H[(size_t)(row0 + r) * DG_DIM + col] = (__bf16)silu_f(acc[i][j][r]);
    }
  }
}

// ---------------------------------------------------------------------------
// GEMM2 + fused causal depthwise conv + silu.  B = permuted w2; lane owns
// d = (n0>>2) + wn*16 + ln; its 4 j-fragments are taps w=0..3 of that d.
// Natural dispatch (R2 lesson).
// ---------------------------------------------------------------------------
__global__ __launch_bounds__(512) void gemm2_conv_silu(
    const __bf16* __restrict__ A, const __bf16* __restrict__ B,
    const float* __restrict__ b2, const float* __restrict__ x,
    float* __restrict__ out) {
  __shared__ __bf16 sA[4 * 8192];
  __shared__ __bf16 sB[4 * 8192];
  const int m0 = blockIdx.y * 256, n0 = blockIdx.x * 256;
  f32x4 acc[8][4] = {};
  gemm_core(A, B, m0, n0, sA, sB, acc);

  const int lane = threadIdx.x & 63;
  const int wv   = threadIdx.x >> 6;
  const int wm   = wv >> 2, wn = wv & 3;
  const int ln   = lane & 15, qd = lane >> 4;

  const int d = (n0 >> 2) + wn * 16 + ln;
  const float4 bias = *(const float4*)(b2 + 4 * d);

#pragma unroll
  for (int i = 0; i < 8; i++) {
    const int m_base = m0 + wm * 16 + i * 32 + qd * 4;   // + r
    const int b  = m_base >> 12;                          // T=4096
    const int tb = m_base & 4095;
    // taps: x[b, tb + s - 3, d] for s = r + j in [0,6]
    float xv[7];
#pragma unroll
    for (int s = 0; s < 7; s++) {
      const int tp = tb + s - 3;
      xv[s] = (tp >= 0) ? x[((size_t)((b << 12) + tp)) * D_DIM + d] : 0.f;
    }
#pragma unroll
    for (int r = 0; r < 4; r++) {
      float y = (acc[i][0][r] + bias.x) * xv[r + 0]
              + (acc[i][1][r] + bias.y) * xv[r + 1]
              + (acc[i][2][r] + bias.z) * xv[r + 2]
              + (acc[i][3][r] + bias.w) * xv[r + 3];
      out[(size_t)(m_base + r) * D_DIM + d] = silu_f(y);
    }
  }
}

extern "C" void kernel_launch(void* const* d_in, const int* in_sizes, int n_in,
                              void* d_out, int out_size, void* d_ws, size_t ws_size,
                              hipStream_t stream) {
  (void)in_sizes; (void)n_in; (void)out_size; (void)ws_size;
  const float* x  = (const float*)d_in[0];
  const float* w1 = (const float*)d_in[1];
  const float* w2 = (const float*)d_in[2];
  const float* b2 = (const float*)d_in[3];
  float* out = (float*)d_out;

  __bf16* xb  = (__bf16*)d_ws;                        // 8192*2048
  __bf16* w1b = xb  + (size_t)M_DIM * D_DIM;          // 2048*2048
  __bf16* w2b = w1b + (size_t)DG_DIM * D_DIM;         // 8192*2048 (permuted)
  __bf16* hb  = w2b + (size_t)N2_DIM * DG_DIM;        // 8192*2048

  {
    int n4 = M_DIM * D_DIM / 4;
    cast_f32_bf16<<<(n4 + 255) / 256, 256, 0, stream>>>(x, xb, n4);
  }
  {
    int n4 = DG_DIM * D_DIM / 4;
    cast_f32_bf16<<<(n4 + 255) / 256, 256, 0, stream>>>(w1, w1b, n4);
  }
  {
    int n4 = N2_DIM * DG_DIM / 4;
    cast_permute_w2<<<(n4 + 255) / 256, 256, 0, stream>>>(w2, w2b, n4);
  }

  gemm1_silu<<<dim3(DG_DIM / 256, M_DIM / 256), 512, 0, stream>>>(xb, w1b, hb);
  gemm2_conv_silu<<<dim3(N2_DIM / 256, M_DIM / 256), 512, 0, stream>>>(
      hb, w2b, b2, x, out);
}